// Round 1
// baseline (1340.323 us; speedup 1.0000x reference)
//
#include <hip/hip_runtime.h>
#include <stdint.h>
#include <math.h>

// ---------------------------------------------------------------------------
// DecoderRNN: 2-layer LSTM (B=32, T=64, E=H=512) + vocab projection (V=50257)
//
// Plan:
//   K1  build_inputs : gather embeddings + features -> inputs_bf [65][32][512]
//   K2  cast weights to bf16 (w_ih0/w_hh0/w_ih1/w_hh1), pad-cast w_out
//   K3  lstm_pipeline: ONE persistent kernel, 64 WGs (32 per layer), layer 1
//       runs one timestep behind layer 0 (software pipeline) => 66 rounds of
//       a device-scope atomic grid barrier. Per-WG: 16 columns of H, weights
//       live in registers (bf16x8 MFMA fragments), gates via mfma 16x16x32.
//       Writes A_bf [2048][512] = h1 rows ordered (b*64 + t) for the GEMM.
//   K4  logits_gemm  : 128x128x(BK=32) bf16 MFMA GEMM, m97 structure
//       (global_load_lds width-16 staging, 2 barriers/K-step), f32 out + bias.
// ---------------------------------------------------------------------------

typedef unsigned short u16;
typedef __bf16 bf16x8 __attribute__((ext_vector_type(8)));
typedef float  f32x4  __attribute__((ext_vector_type(4)));

#define BATCH   32
#define SEQT    64
#define NSTEP   65            // T+1 timesteps
#define EMB     512
#define HID     512
#define VOCAB   50257
#define VPAD    50304         // 393*128, zero-padded rows for tail tile
#define NWG_LSTM 64

// f32 -> bf16 round-to-nearest-even
static __device__ __forceinline__ u16 f2bf(float f) {
  unsigned u = __float_as_uint(f);
  u += 0x7FFFu + ((u >> 16) & 1u);
  return (u16)(u >> 16);
}

// One MFMA A/B fragment = 8 contiguous bf16 (16B) from a row-major matrix.
// lane l: row = l&15 (caller bakes in), k = k0 + 8*(l>>4) (caller bakes in).
static __device__ __forceinline__ bf16x8 ld_frag(const u16* p16) {
  union { uint4 u; bf16x8 v; } f;
  f.u = *(const uint4*)p16;
  return f.v;
}

static __device__ __forceinline__ float sigmoidf_(float x) {
  return 1.0f / (1.0f + __expf(-x));
}

// ---------------------------------------------------------------------------
// K1: inputs_bf[t][b][e] : t=0 -> features, t>=1 -> embed_w[captions[b][t-1]]
// ---------------------------------------------------------------------------
__global__ void build_inputs(const float* __restrict__ features,
                             const int*   __restrict__ captions,
                             const float* __restrict__ embed_w,
                             u16* __restrict__ dst) {
  int idx = blockIdx.x * blockDim.x + threadIdx.x;
  const int n = NSTEP * BATCH * EMB;
  if (idx >= n) return;
  int e = idx & (EMB - 1);
  int rem = idx >> 9;           // /512
  int b = rem & (BATCH - 1);
  int t = rem >> 5;             // /32
  float v;
  if (t == 0) v = features[b * EMB + e];
  else        v = embed_w[(size_t)captions[b * SEQT + (t - 1)] * EMB + e];
  dst[idx] = f2bf(v);
}

// ---------------------------------------------------------------------------
// K2: f32 -> bf16 cast (vectorized x4); and pad-cast for w_out
// ---------------------------------------------------------------------------
__global__ void cast_bf16(const float* __restrict__ src, u16* __restrict__ dst, int n4) {
  int i = blockIdx.x * blockDim.x + threadIdx.x;
  if (i >= n4) return;
  float4 v = ((const float4*)src)[i];
  ushort4 o;
  o.x = f2bf(v.x); o.y = f2bf(v.y); o.z = f2bf(v.z); o.w = f2bf(v.w);
  ((ushort4*)dst)[i] = o;
}

__global__ void cast_pad_wout(const float* __restrict__ src, u16* __restrict__ dst) {
  int i = blockIdx.x * blockDim.x + threadIdx.x;
  const int n4 = VPAD * 512 / 4;
  const int nsrc4 = VOCAB * 512 / 4;   // divisible by 4
  if (i >= n4) return;
  ushort4 o;
  if (i < nsrc4) {
    float4 v = ((const float4*)src)[i];
    o.x = f2bf(v.x); o.y = f2bf(v.y); o.z = f2bf(v.z); o.w = f2bf(v.w);
  } else {
    o.x = 0; o.y = 0; o.z = 0; o.w = 0;
  }
  ((ushort4*)dst)[i] = o;
}

// ---------------------------------------------------------------------------
// K3: persistent pipelined 2-layer LSTM.
//  grid = 64 WGs x 256 threads. WG 0..31 = layer0 (j-slice = wg*16),
//  WG 32..63 = layer1. Round r: layer0 does t=r (r<=64), layer1 does t=r-1.
//  Wave w (0..3) owns gate w: rows n = w*512 + j0 + (lane&15) of w_ih/w_hh.
//  gates[32 x 16] per gate via mfma_f32_16x16x32_bf16, A = activations
//  (read straight from global, 16B/frag), B = weight frags kept in VGPRs.
// ---------------------------------------------------------------------------
__global__ __launch_bounds__(256, 1)
void lstm_pipeline(const u16* __restrict__ inputs_bf,   // [65][32][512]
                   const u16* __restrict__ wih0, const u16* __restrict__ whh0,
                   const float* __restrict__ b0,
                   const u16* __restrict__ wih1, const u16* __restrict__ whh1,
                   const float* __restrict__ b1,
                   u16* __restrict__ h0_state,   // [2][32][512] ping-pong
                   u16* __restrict__ h1_state,   // [2][32][512]
                   u16* __restrict__ A_bf,       // [2048][512] rows (b*64+t)
                   unsigned int* __restrict__ ctr) {
  const int wg    = blockIdx.x;
  const int layer = wg >> 5;
  const int j0    = (wg & 31) * 16;
  const int tid   = threadIdx.x;
  const int lane  = tid & 63;
  const int wv    = tid >> 6;       // wave index == gate index
  const int l15   = lane & 15;
  const int lg    = lane >> 4;

  const u16*   wih  = layer ? wih1 : wih0;
  const u16*   whh  = layer ? whh1 : whh0;
  const float* bias = layer ? b1 : b0;

  __shared__ float gates_lds[4][32][16];   // 8 KB
  __shared__ float c_lds[32][16];          // 2 KB
  __shared__ float bias_lds[4][16];

  for (int i = tid; i < BATCH * 16; i += 256) c_lds[i >> 4][i & 15] = 0.0f;
  if (tid < 64) bias_lds[tid >> 4][tid & 15] = bias[(tid >> 4) * HID + j0 + (tid & 15)];

  // Load this wave's weight B-fragments into registers (held all 65 steps).
  // B[k][n] = W[n][k]; lane l: n-row = wv*512 + j0 + l15, k = kk*32 + 8*lg + 0..7
  bf16x8 wih_f[16], whh_f[16];
  {
    const u16* wr = wih + (size_t)(wv * HID + j0 + l15) * 512;
    const u16* hr = whh + (size_t)(wv * HID + j0 + l15) * 512;
#pragma unroll
    for (int kk = 0; kk < 16; ++kk) {
      int k0 = kk * 32 + 8 * lg;
      wih_f[kk] = ld_frag(wr + k0);
      whh_f[kk] = ld_frag(hr + k0);
    }
  }
  __syncthreads();

  for (int r = 0; r <= NSTEP; ++r) {
    const int t = (layer == 0) ? r : (r - 1);
    const bool active = (t >= 0) && (t < NSTEP);

    if (active) {
      const u16* xA = (layer == 0) ? (inputs_bf + (size_t)t * (BATCH * EMB))
                                   : (h0_state + (size_t)(t & 1) * (BATCH * HID));
      const u16* hA = (layer == 0) ? (h0_state + (size_t)((t - 1) & 1) * (BATCH * HID))
                                   : (h1_state + (size_t)((t - 1) & 1) * (BATCH * HID));
      f32x4 acc0 = {0.f, 0.f, 0.f, 0.f};
      f32x4 acc1 = {0.f, 0.f, 0.f, 0.f};
      const u16* xr0 = xA + (size_t)l15 * 512;        // batch rows 0..15
      const u16* xr1 = xA + (size_t)(16 + l15) * 512; // batch rows 16..31
#pragma unroll
      for (int kk = 0; kk < 16; ++kk) {
        int k0 = kk * 32 + 8 * lg;
        bf16x8 a0 = ld_frag(xr0 + k0);
        bf16x8 a1 = ld_frag(xr1 + k0);
        acc0 = __builtin_amdgcn_mfma_f32_16x16x32_bf16(a0, wih_f[kk], acc0, 0, 0, 0);
        acc1 = __builtin_amdgcn_mfma_f32_16x16x32_bf16(a1, wih_f[kk], acc1, 0, 0, 0);
      }
      if (t > 0) {
        const u16* hr0 = hA + (size_t)l15 * 512;
        const u16* hr1 = hA + (size_t)(16 + l15) * 512;
#pragma unroll
        for (int kk = 0; kk < 16; ++kk) {
          int k0 = kk * 32 + 8 * lg;
          bf16x8 a0 = ld_frag(hr0 + k0);
          bf16x8 a1 = ld_frag(hr1 + k0);
          acc0 = __builtin_amdgcn_mfma_f32_16x16x32_bf16(a0, whh_f[kk], acc0, 0, 0, 0);
          acc1 = __builtin_amdgcn_mfma_f32_16x16x32_bf16(a1, whh_f[kk], acc1, 0, 0, 0);
        }
      }
      // C layout: col = lane&15, row = 4*(lane>>4)+reg
#pragma unroll
      for (int rr = 0; rr < 4; ++rr) {
        gates_lds[wv][4 * lg + rr][l15]      = acc0[rr];
        gates_lds[wv][16 + 4 * lg + rr][l15] = acc1[rr];
      }
    }
    __syncthreads();
    if (active) {
      // pointwise over 512 (b,jj) pairs, 2 per thread
#pragma unroll
      for (int e = 0; e < 2; ++e) {
        int idx = tid + e * 256;
        int b = idx >> 4, jj = idx & 15;
        float gi = gates_lds[0][b][jj] + bias_lds[0][jj];
        float gf = gates_lds[1][b][jj] + bias_lds[1][jj];
        float gg = gates_lds[2][b][jj] + bias_lds[2][jj];
        float go = gates_lds[3][b][jj] + bias_lds[3][jj];
        float cprev = c_lds[b][jj];
        float cn = sigmoidf_(gf) * cprev + sigmoidf_(gi) * tanhf(gg);
        c_lds[b][jj] = cn;
        float hn = sigmoidf_(go) * tanhf(cn);
        u16 hb = f2bf(hn);
        u16* hs = (layer == 0 ? h0_state : h1_state) + (size_t)(t & 1) * (BATCH * HID);
        hs[b * HID + j0 + jj] = hb;
        if (layer == 1 && t >= 1)
          A_bf[(size_t)(b * SEQT + (t - 1)) * HID + j0 + jj] = hb;
      }
    }
    // grid barrier (device-scope), skip after last round
    if (r < NSTEP) {
      __syncthreads();
      if (tid == 0) {
        __threadfence();
        __hip_atomic_fetch_add(ctr, 1u, __ATOMIC_RELAXED, __HIP_MEMORY_SCOPE_AGENT);
        const unsigned target = (unsigned)(r + 1) * NWG_LSTM;
        while (__hip_atomic_load(ctr, __ATOMIC_RELAXED, __HIP_MEMORY_SCOPE_AGENT) < target) {}
        __threadfence();
      }
      __syncthreads();
    }
  }
}

// ---------------------------------------------------------------------------
// K4: logits GEMM. C[m][v] = A[m][:] . Bw[v][:] + b_out[v]
//  A = A_bf [2048][512] bf16, Bw = w_out_bf [50304][512] bf16, out f32.
//  128x128 tile, BK=32, 4 waves (2x2 of 64x64), m97 staging structure.
// ---------------------------------------------------------------------------
__global__ __launch_bounds__(256)
void logits_gemm(const u16* __restrict__ Ag,
                 const u16* __restrict__ Bg,
                 const float* __restrict__ b_out,
                 float* __restrict__ out) {
  const int mt = blockIdx.x;      // 0..15
  const int nt = blockIdx.y;      // 0..392
  const int m0 = mt * 128, v0 = nt * 128;
  const int tid  = threadIdx.x;
  const int lane = tid & 63;
  const int wv   = tid >> 6;
  const int l15  = lane & 15;
  const int lg   = lane >> 4;
  const int wm = (wv & 1) * 64;
  const int wn = (wv >> 1) * 64;

  __shared__ u16 As[128 * 32];   // 8 KB, row-major [row][32]
  __shared__ u16 Bs[128 * 32];   // 8 KB

  f32x4 acc[4][4];
#pragma unroll
  for (int mi = 0; mi < 4; ++mi)
#pragma unroll
    for (int ni = 0; ni < 4; ++ni)
      acc[mi][ni] = (f32x4){0.f, 0.f, 0.f, 0.f};

  for (int kt = 0; kt < 16; ++kt) {
    // stage A,B tiles: each wave stages rows [wv*32, wv*32+32), 16B/lane/call
#pragma unroll
    for (int c = 0; c < 2; ++c) {
      int f16 = wv * 128 + c * 64 + lane;     // 16B-chunk index, 512 total
      int row = f16 >> 2;
      int kc  = (f16 & 3) << 3;
      const u16* ga = Ag + (size_t)(m0 + row) * 512 + kt * 32 + kc;
      const u16* gb = Bg + (size_t)(v0 + row) * 512 + kt * 32 + kc;
      u16* la = &As[(wv * 128 + c * 64) * 8];
      u16* lb = &Bs[(wv * 128 + c * 64) * 8];
      __builtin_amdgcn_global_load_lds(
          (const __attribute__((address_space(1))) void*)ga,
          (__attribute__((address_space(3))) void*)la, 16, 0, 0);
      __builtin_amdgcn_global_load_lds(
          (const __attribute__((address_space(1))) void*)gb,
          (__attribute__((address_space(3))) void*)lb, 16, 0, 0);
    }
    asm volatile("s_waitcnt vmcnt(0)" ::: "memory");
    __syncthreads();

    bf16x8 af[4], bfr[4];
#pragma unroll
    for (int i = 0; i < 4; ++i) {
      af[i]  = ld_frag(&As[(wm + i * 16 + l15) * 32 + 8 * lg]);
      bfr[i] = ld_frag(&Bs[(wn + i * 16 + l15) * 32 + 8 * lg]);
    }
#pragma unroll
    for (int mi = 0; mi < 4; ++mi)
#pragma unroll
      for (int ni = 0; ni < 4; ++ni)
        acc[mi][ni] = __builtin_amdgcn_mfma_f32_16x16x32_bf16(af[mi], bfr[ni], acc[mi][ni], 0, 0, 0);
    __syncthreads();
  }

  // epilogue: C row = 4*lg + reg (within 16-tile), col = l15
#pragma unroll
  for (int ni = 0; ni < 4; ++ni) {
    int v = v0 + wn + ni * 16 + l15;
    bool vok = (v < VOCAB);
    float bo = vok ? b_out[v] : 0.0f;
#pragma unroll
    for (int mi = 0; mi < 4; ++mi) {
      int mbase = m0 + wm + mi * 16 + 4 * lg;
#pragma unroll
      for (int rr = 0; rr < 4; ++rr) {
        if (vok) out[(size_t)(mbase + rr) * VOCAB + v] = acc[mi][ni][rr] + bo;
      }
    }
  }
}

// ---------------------------------------------------------------------------
// host
// ---------------------------------------------------------------------------
extern "C" void kernel_launch(void* const* d_in, const int* in_sizes, int n_in,
                              void* d_out, int out_size, void* d_ws, size_t ws_size,
                              hipStream_t stream) {
  const float* features = (const float*)d_in[0];
  const int*   captions = (const int*)d_in[1];
  const float* embed_w  = (const float*)d_in[2];
  const float* w_ih0    = (const float*)d_in[3];
  const float* w_hh0    = (const float*)d_in[4];
  const float* b0       = (const float*)d_in[5];
  const float* w_ih1    = (const float*)d_in[6];
  const float* w_hh1    = (const float*)d_in[7];
  const float* b1       = (const float*)d_in[8];
  const float* w_out    = (const float*)d_in[9];
  const float* b_out    = (const float*)d_in[10];
  float* out = (float*)d_out;

  char* ws = (char*)d_ws;
  size_t off = 0;
  auto alloc = [&](size_t bytes) -> void* {
    void* p = ws + off;
    off = (off + bytes + 255) & ~(size_t)255;
    return p;
  };
  unsigned int* ctr = (unsigned int*)alloc(256);
  u16* inputs_bf = (u16*)alloc((size_t)NSTEP * BATCH * EMB * 2);
  u16* wih0_bf   = (u16*)alloc((size_t)4 * HID * EMB * 2);
  u16* whh0_bf   = (u16*)alloc((size_t)4 * HID * HID * 2);
  u16* wih1_bf   = (u16*)alloc((size_t)4 * HID * HID * 2);
  u16* whh1_bf   = (u16*)alloc((size_t)4 * HID * HID * 2);
  u16* wout_bf   = (u16*)alloc((size_t)VPAD * HID * 2);
  u16* h0s       = (u16*)alloc((size_t)2 * BATCH * HID * 2);
  u16* h1s       = (u16*)alloc((size_t)2 * BATCH * HID * 2);
  u16* A_bf      = (u16*)alloc((size_t)BATCH * SEQT * HID * 2);
  (void)ws_size; (void)in_sizes; (void)n_in; (void)out_size;

  hipMemsetAsync(ctr, 0, 256, stream);

  {
    int n = NSTEP * BATCH * EMB;
    build_inputs<<<(n + 255) / 256, 256, 0, stream>>>(features, captions, embed_w, inputs_bf);
  }
  {
    int n4 = 4 * HID * EMB / 4;
    cast_bf16<<<(n4 + 255) / 256, 256, 0, stream>>>(w_ih0, wih0_bf, n4);
    cast_bf16<<<(n4 + 255) / 256, 256, 0, stream>>>(w_hh0, whh0_bf, n4);
    cast_bf16<<<(n4 + 255) / 256, 256, 0, stream>>>(w_ih1, wih1_bf, n4);
    cast_bf16<<<(n4 + 255) / 256, 256, 0, stream>>>(w_hh1, whh1_bf, n4);
  }
  {
    int n4 = VPAD * 512 / 4;
    cast_pad_wout<<<(n4 + 255) / 256, 256, 0, stream>>>(w_out, wout_bf);
  }
  lstm_pipeline<<<NWG_LSTM, 256, 0, stream>>>(
      inputs_bf, wih0_bf, whh0_bf, b0, wih1_bf, whh1_bf, b1,
      h0s, h1s, A_bf, ctr);
  {
    dim3 grid(16, 393, 1);
    logits_gemm<<<grid, 256, 0, stream>>>(A_bf, wout_bf, b_out, out);
  }
}

// Round 2
// 1090.256 us; speedup vs baseline: 1.2294x; 1.2294x over previous
//
#include <hip/hip_runtime.h>
#include <stdint.h>
#include <math.h>

// ---------------------------------------------------------------------------
// DecoderRNN: 2-layer LSTM (B=32, T=64, E=H=512) + vocab projection (V=50257)
//
//   K1  build_inputs : gather embeddings + features -> inputs_bf [65][32][512]
//   K2  cast weights to bf16, pad-cast w_out
//   K3  lstm_pipeline: persistent kernel, 64 WGs (32/layer), layer-1 one step
//       behind layer-0. Grid sync via FENCELESS slot barrier: h-state moves
//       through the coherent point (sc0 sc1 bypass loads/stores), so no L2
//       writeback/invalidate is ever needed. 66 rounds.
//   K4  logits_gemm  : 128x128x32 bf16 MFMA GEMM (m97 structure), f32 + bias.
// ---------------------------------------------------------------------------

typedef unsigned short u16;
typedef __bf16 bf16x8 __attribute__((ext_vector_type(8)));
typedef float  f32x4  __attribute__((ext_vector_type(4)));

#define BATCH   32
#define SEQT    64
#define NSTEP   65            // T+1 timesteps
#define EMB     512
#define HID     512
#define VOCAB   50257
#define VPAD    50304         // 393*128
#define NWG_LSTM 64

static __device__ __forceinline__ u16 f2bf(float f) {
  unsigned u = __float_as_uint(f);
  u += 0x7FFFu + ((u >> 16) & 1u);
  return (u16)(u >> 16);
}

static __device__ __forceinline__ bf16x8 ld_frag(const u16* p16) {
  union { uint4 u; bf16x8 v; } f;
  f.u = *(const uint4*)p16;
  return f.v;
}

// Coherent-point (bypass L1+L2) 16B load. Caller MUST do
// s_waitcnt vmcnt(0) + sched_barrier(0) before using the result.
static __device__ __forceinline__ bf16x8 ld_frag_sys(const u16* p16) {
  union { uint4 u; bf16x8 v; } f;
  asm volatile("global_load_dwordx4 %0, %1, off sc0 sc1"
               : "=v"(f.u) : "v"(p16));
  return f.v;
}

// Coherent-point 8B store (write-through past non-coherent L2).
static __device__ __forceinline__ void st_sys64(u16* p, unsigned long long v) {
  asm volatile("global_store_dwordx2 %0, %1, off sc0 sc1"
               :: "v"(p), "v"(v) : "memory");
}

static __device__ __forceinline__ float sigmoidf_(float x) {
  return 1.0f / (1.0f + __expf(-x));
}

// ---------------------------------------------------------------------------
// K1
// ---------------------------------------------------------------------------
__global__ void build_inputs(const float* __restrict__ features,
                             const int*   __restrict__ captions,
                             const float* __restrict__ embed_w,
                             u16* __restrict__ dst) {
  int idx = blockIdx.x * blockDim.x + threadIdx.x;
  const int n = NSTEP * BATCH * EMB;
  if (idx >= n) return;
  int e = idx & (EMB - 1);
  int rem = idx >> 9;
  int b = rem & (BATCH - 1);
  int t = rem >> 5;
  float v;
  if (t == 0) v = features[b * EMB + e];
  else        v = embed_w[(size_t)captions[b * SEQT + (t - 1)] * EMB + e];
  dst[idx] = f2bf(v);
}

// ---------------------------------------------------------------------------
// K2
// ---------------------------------------------------------------------------
__global__ void cast_bf16(const float* __restrict__ src, u16* __restrict__ dst, int n4) {
  int i = blockIdx.x * blockDim.x + threadIdx.x;
  if (i >= n4) return;
  float4 v = ((const float4*)src)[i];
  ushort4 o;
  o.x = f2bf(v.x); o.y = f2bf(v.y); o.z = f2bf(v.z); o.w = f2bf(v.w);
  ((ushort4*)dst)[i] = o;
}

__global__ void cast_pad_wout(const float* __restrict__ src, u16* __restrict__ dst) {
  int i = blockIdx.x * blockDim.x + threadIdx.x;
  const int n4 = VPAD * 512 / 4;
  const int nsrc4 = VOCAB * 512 / 4;
  if (i >= n4) return;
  ushort4 o;
  if (i < nsrc4) {
    float4 v = ((const float4*)src)[i];
    o.x = f2bf(v.x); o.y = f2bf(v.y); o.z = f2bf(v.z); o.w = f2bf(v.w);
  } else {
    o.x = 0; o.y = 0; o.z = 0; o.w = 0;
  }
  ((ushort4*)dst)[i] = o;
}

// ---------------------------------------------------------------------------
// K3: persistent pipelined 2-layer LSTM, fenceless slot barrier.
// ---------------------------------------------------------------------------
__global__ __launch_bounds__(256, 1)
void lstm_pipeline(const u16* __restrict__ inputs_bf,
                   const u16* __restrict__ wih0, const u16* __restrict__ whh0,
                   const float* __restrict__ b0,
                   const u16* __restrict__ wih1, const u16* __restrict__ whh1,
                   const float* __restrict__ b1,
                   u16* h0_state,                // [2][32][512] ping-pong
                   u16* h1_state,                // [2][32][512]
                   u16* __restrict__ A_bf,       // [2048][512] rows (b*64+t)
                   unsigned int* slots) {        // [64] round counters
  const int wg    = blockIdx.x;
  const int layer = wg >> 5;
  const int j0    = (wg & 31) * 16;
  const int tid   = threadIdx.x;
  const int lane  = tid & 63;
  const int wv    = tid >> 6;       // wave index == gate index
  const int l15   = lane & 15;
  const int lg    = lane >> 4;

  const u16*   wih  = layer ? wih1 : wih0;
  const u16*   whh  = layer ? whh1 : whh0;
  const float* bias = layer ? b1 : b0;

  __shared__ float gates_lds[4][32][16];
  __shared__ float c_lds[32][16];
  __shared__ float bias_lds[4][16];

  for (int i = tid; i < BATCH * 16; i += 256) c_lds[i >> 4][i & 15] = 0.0f;
  if (tid < 64) bias_lds[tid >> 4][tid & 15] = bias[(tid >> 4) * HID + j0 + (tid & 15)];

  // Weight B-fragments in registers for all 65 steps.
  // B[k][n] = W[n][k]; lane l: n = wv*512 + j0 + l15, k = kk*32 + 8*lg + 0..7
  bf16x8 wih_f[16], whh_f[16];
  {
    const u16* wr = wih + (size_t)(wv * HID + j0 + l15) * 512;
    const u16* hr = whh + (size_t)(wv * HID + j0 + l15) * 512;
#pragma unroll
    for (int kk = 0; kk < 16; ++kk) {
      int k0 = kk * 32 + 8 * lg;
      wih_f[kk] = ld_frag(wr + k0);
      whh_f[kk] = ld_frag(hr + k0);
    }
  }
  __syncthreads();

  for (int r = 0; r <= NSTEP; ++r) {
    const int t = (layer == 0) ? r : (r - 1);
    const bool active = (t >= 0) && (t < NSTEP);

    if (active) {
      const u16* xA = (layer == 0) ? (inputs_bf + (size_t)t * (BATCH * EMB))
                                   : (h0_state + (size_t)(t & 1) * (BATCH * HID));
      const u16* hA = (layer == 0) ? (h0_state + (size_t)((t - 1) & 1) * (BATCH * HID))
                                   : (h1_state + (size_t)((t - 1) & 1) * (BATCH * HID));
      const u16* xr0 = xA + (size_t)l15 * 512;
      const u16* xr1 = xA + (size_t)(16 + l15) * 512;
      const u16* hr0 = hA + (size_t)l15 * 512;
      const u16* hr1 = hA + (size_t)(16 + l15) * 512;
      const bool xbyp = (layer == 1);   // layer-1's x is h0 -> bypass loads
      const bool useh = (t > 0);        // h(-1) == 0

      f32x4 acc0 = {0.f, 0.f, 0.f, 0.f};
      f32x4 acc1 = {0.f, 0.f, 0.f, 0.f};

#pragma unroll
      for (int kb = 0; kb < 2; ++kb) {
        bf16x8 xa0[8], xa1[8], ha0[8], ha1[8];
#pragma unroll
        for (int i = 0; i < 8; ++i) {
          const int k0 = (kb * 8 + i) * 32 + 8 * lg;
          if (xbyp) { xa0[i] = ld_frag_sys(xr0 + k0); xa1[i] = ld_frag_sys(xr1 + k0); }
          else      { xa0[i] = ld_frag(xr0 + k0);     xa1[i] = ld_frag(xr1 + k0); }
          if (useh) { ha0[i] = ld_frag_sys(hr0 + k0); ha1[i] = ld_frag_sys(hr1 + k0); }
        }
        asm volatile("s_waitcnt vmcnt(0)" ::: "memory");
        __builtin_amdgcn_sched_barrier(0);
#pragma unroll
        for (int i = 0; i < 8; ++i) {
          const int kk = kb * 8 + i;
          acc0 = __builtin_amdgcn_mfma_f32_16x16x32_bf16(xa0[i], wih_f[kk], acc0, 0, 0, 0);
          acc1 = __builtin_amdgcn_mfma_f32_16x16x32_bf16(xa1[i], wih_f[kk], acc1, 0, 0, 0);
          if (useh) {
            acc0 = __builtin_amdgcn_mfma_f32_16x16x32_bf16(ha0[i], whh_f[kk], acc0, 0, 0, 0);
            acc1 = __builtin_amdgcn_mfma_f32_16x16x32_bf16(ha1[i], whh_f[kk], acc1, 0, 0, 0);
          }
        }
      }
      // C layout: col = lane&15, row = 4*(lane>>4)+reg
#pragma unroll
      for (int rr = 0; rr < 4; ++rr) {
        gates_lds[wv][4 * lg + rr][l15]      = acc0[rr];
        gates_lds[wv][16 + 4 * lg + rr][l15] = acc1[rr];
      }
    }
    __syncthreads();

    if (active && tid < 128) {
      // 128 threads x 4 consecutive jj each -> 8B packed stores
      const int b = tid >> 2;
      const int q = (tid & 3) * 4;
      float hv[4];
#pragma unroll
      for (int u = 0; u < 4; ++u) {
        const int jj = q + u;
        float gi = gates_lds[0][b][jj] + bias_lds[0][jj];
        float gf = gates_lds[1][b][jj] + bias_lds[1][jj];
        float gg = gates_lds[2][b][jj] + bias_lds[2][jj];
        float go = gates_lds[3][b][jj] + bias_lds[3][jj];
        float cp = c_lds[b][jj];
        float cn = sigmoidf_(gf) * cp + sigmoidf_(gi) * tanhf(gg);
        c_lds[b][jj] = cn;
        hv[u] = sigmoidf_(go) * tanhf(cn);
      }
      union { ushort4 s; unsigned long long v; } pk;
      pk.s.x = f2bf(hv[0]); pk.s.y = f2bf(hv[1]);
      pk.s.z = f2bf(hv[2]); pk.s.w = f2bf(hv[3]);
      u16* hs = (layer ? h1_state : h0_state) + (size_t)(t & 1) * (BATCH * HID);
      st_sys64(hs + b * HID + j0 + q, pk.v);
      if (layer == 1 && t >= 1)
        *(unsigned long long*)(A_bf + (size_t)(b * SEQT + (t - 1)) * HID + j0 + q) = pk.v;
    }
    // drain this wave's stores to the coherent point before signaling
    asm volatile("s_waitcnt vmcnt(0)" ::: "memory");
    __syncthreads();

    if (r < NSTEP) {
      if (tid == 0)
        __hip_atomic_store(&slots[wg], (unsigned)(r + 1),
                           __ATOMIC_RELAXED, __HIP_MEMORY_SCOPE_SYSTEM);
      if (tid < 64) {
        const unsigned tgt = (unsigned)(r + 1);
        for (;;) {
          unsigned v = __hip_atomic_load(&slots[tid], __ATOMIC_RELAXED,
                                         __HIP_MEMORY_SCOPE_SYSTEM);
          if (__all((int)(v >= tgt))) break;
        }
      }
      __syncthreads();
    }
  }
}

// ---------------------------------------------------------------------------
// K4: logits GEMM (unchanged this round).
// ---------------------------------------------------------------------------
__global__ __launch_bounds__(256)
void logits_gemm(const u16* __restrict__ Ag,
                 const u16* __restrict__ Bg,
                 const float* __restrict__ b_out,
                 float* __restrict__ out) {
  const int mt = blockIdx.x;
  const int nt = blockIdx.y;
  const int m0 = mt * 128, v0 = nt * 128;
  const int tid  = threadIdx.x;
  const int lane = tid & 63;
  const int wv   = tid >> 6;
  const int l15  = lane & 15;
  const int lg   = lane >> 4;
  const int wm = (wv & 1) * 64;
  const int wn = (wv >> 1) * 64;

  __shared__ u16 As[128 * 32];
  __shared__ u16 Bs[128 * 32];

  f32x4 acc[4][4];
#pragma unroll
  for (int mi = 0; mi < 4; ++mi)
#pragma unroll
    for (int ni = 0; ni < 4; ++ni)
      acc[mi][ni] = (f32x4){0.f, 0.f, 0.f, 0.f};

  for (int kt = 0; kt < 16; ++kt) {
#pragma unroll
    for (int c = 0; c < 2; ++c) {
      int f16 = wv * 128 + c * 64 + lane;
      int row = f16 >> 2;
      int kc  = (f16 & 3) << 3;
      const u16* ga = Ag + (size_t)(m0 + row) * 512 + kt * 32 + kc;
      const u16* gb = Bg + (size_t)(v0 + row) * 512 + kt * 32 + kc;
      u16* la = &As[(wv * 128 + c * 64) * 8];
      u16* lb = &Bs[(wv * 128 + c * 64) * 8];
      __builtin_amdgcn_global_load_lds(
          (const __attribute__((address_space(1))) void*)ga,
          (__attribute__((address_space(3))) void*)la, 16, 0, 0);
      __builtin_amdgcn_global_load_lds(
          (const __attribute__((address_space(1))) void*)gb,
          (__attribute__((address_space(3))) void*)lb, 16, 0, 0);
    }
    asm volatile("s_waitcnt vmcnt(0)" ::: "memory");
    __syncthreads();

    bf16x8 af[4], bfr[4];
#pragma unroll
    for (int i = 0; i < 4; ++i) {
      af[i]  = ld_frag(&As[(wm + i * 16 + l15) * 32 + 8 * lg]);
      bfr[i] = ld_frag(&Bs[(wn + i * 16 + l15) * 32 + 8 * lg]);
    }
#pragma unroll
    for (int mi = 0; mi < 4; ++mi)
#pragma unroll
      for (int ni = 0; ni < 4; ++ni)
        acc[mi][ni] = __builtin_amdgcn_mfma_f32_16x16x32_bf16(af[mi], bfr[ni], acc[mi][ni], 0, 0, 0);
    __syncthreads();
  }

#pragma unroll
  for (int ni = 0; ni < 4; ++ni) {
    int v = v0 + wn + ni * 16 + l15;
    bool vok = (v < VOCAB);
    float bo = vok ? b_out[v] : 0.0f;
#pragma unroll
    for (int mi = 0; mi < 4; ++mi) {
      int mbase = m0 + wm + mi * 16 + 4 * lg;
#pragma unroll
      for (int rr = 0; rr < 4; ++rr) {
        if (vok) out[(size_t)(mbase + rr) * VOCAB + v] = acc[mi][ni][rr] + bo;
      }
    }
  }
}

// ---------------------------------------------------------------------------
// host
// ---------------------------------------------------------------------------
extern "C" void kernel_launch(void* const* d_in, const int* in_sizes, int n_in,
                              void* d_out, int out_size, void* d_ws, size_t ws_size,
                              hipStream_t stream) {
  const float* features = (const float*)d_in[0];
  const int*   captions = (const int*)d_in[1];
  const float* embed_w  = (const float*)d_in[2];
  const float* w_ih0    = (const float*)d_in[3];
  const float* w_hh0    = (const float*)d_in[4];
  const float* b0       = (const float*)d_in[5];
  const float* w_ih1    = (const float*)d_in[6];
  const float* w_hh1    = (const float*)d_in[7];
  const float* b1       = (const float*)d_in[8];
  const float* w_out    = (const float*)d_in[9];
  const float* b_out    = (const float*)d_in[10];
  float* out = (float*)d_out;

  char* ws = (char*)d_ws;
  size_t off = 0;
  auto alloc = [&](size_t bytes) -> void* {
    void* p = ws + off;
    off = (off + bytes + 255) & ~(size_t)255;
    return p;
  };
  unsigned int* slots = (unsigned int*)alloc(256);
  u16* inputs_bf = (u16*)alloc((size_t)NSTEP * BATCH * EMB * 2);
  u16* wih0_bf   = (u16*)alloc((size_t)4 * HID * EMB * 2);
  u16* whh0_bf   = (u16*)alloc((size_t)4 * HID * HID * 2);
  u16* wih1_bf   = (u16*)alloc((size_t)4 * HID * HID * 2);
  u16* whh1_bf   = (u16*)alloc((size_t)4 * HID * HID * 2);
  u16* wout_bf   = (u16*)alloc((size_t)VPAD * HID * 2);
  u16* h0s       = (u16*)alloc((size_t)2 * BATCH * HID * 2);
  u16* h1s       = (u16*)alloc((size_t)2 * BATCH * HID * 2);
  u16* A_bf      = (u16*)alloc((size_t)BATCH * SEQT * HID * 2);
  (void)ws_size; (void)in_sizes; (void)n_in; (void)out_size;

  hipMemsetAsync(slots, 0, 256, stream);

  {
    int n = NSTEP * BATCH * EMB;
    build_inputs<<<(n + 255) / 256, 256, 0, stream>>>(features, captions, embed_w, inputs_bf);
  }
  {
    int n4 = 4 * HID * EMB / 4;
    cast_bf16<<<(n4 + 255) / 256, 256, 0, stream>>>(w_ih0, wih0_bf, n4);
    cast_bf16<<<(n4 + 255) / 256, 256, 0, stream>>>(w_hh0, whh0_bf, n4);
    cast_bf16<<<(n4 + 255) / 256, 256, 0, stream>>>(w_ih1, wih1_bf, n4);
    cast_bf16<<<(n4 + 255) / 256, 256, 0, stream>>>(w_hh1, whh1_bf, n4);
  }
  {
    int n4 = VPAD * 512 / 4;
    cast_pad_wout<<<(n4 + 255) / 256, 256, 0, stream>>>(w_out, wout_bf);
  }
  lstm_pipeline<<<NWG_LSTM, 256, 0, stream>>>(
      inputs_bf, wih0_bf, whh0_bf, b0, wih1_bf, whh1_bf, b1,
      h0s, h1s, A_bf, slots);
  {
    dim3 grid(16, 393, 1);
    logits_gemm<<<grid, 256, 0, stream>>>(A_bf, wout_bf, b_out, out);
  }
}

// Round 3
// 924.054 us; speedup vs baseline: 1.4505x; 1.1799x over previous
//
#include <hip/hip_runtime.h>
#include <stdint.h>
#include <math.h>

// ---------------------------------------------------------------------------
// DecoderRNN: 2-layer LSTM (B=32, T=64, E=H=512) + vocab projection (V=50257)
//
//   K1  build_inputs : gather embeddings + features -> inputs_bf [65][32][512]
//   K2  cast weights to bf16, pad-cast w_out
//   K3  lstm_pipeline: persistent kernel, 64 WGs (32/layer). All h timesteps
//       stored (no WAR) -> layer 0 free-runs; layer 1 chases via per-layer
//       single-word counters (atomic_add signal, single-lane s_sleep poll).
//       h exchanged through coherent point (sc0 sc1), NO fences anywhere.
//       Per round: x-phase (loads+MFMA) BEFORE poll -> only h-chain after.
//   K4  logits_gemm  : 128x128x32 bf16 MFMA GEMM (m97 structure), f32 + bias.
// ---------------------------------------------------------------------------

typedef unsigned short u16;
typedef __bf16 bf16x8 __attribute__((ext_vector_type(8)));
typedef float  f32x4  __attribute__((ext_vector_type(4)));

#define BATCH   32
#define SEQT    64
#define NSTEP   65            // T+1 timesteps
#define EMB     512
#define HID     512
#define VOCAB   50257
#define VPAD    50304         // 393*128
#define NWG_LSTM 64

static __device__ __forceinline__ u16 f2bf(float f) {
  unsigned u = __float_as_uint(f);
  u += 0x7FFFu + ((u >> 16) & 1u);
  return (u16)(u >> 16);
}

static __device__ __forceinline__ bf16x8 ld_frag(const u16* p16) {
  union { uint4 u; bf16x8 v; } f;
  f.u = *(const uint4*)p16;
  return f.v;
}

// Coherent-point (bypass L1+L2) 16B load. Caller MUST do
// s_waitcnt vmcnt(0) + sched_barrier(0) before using the result.
static __device__ __forceinline__ bf16x8 ld_frag_sys(const u16* p16) {
  union { uint4 u; bf16x8 v; } f;
  asm volatile("global_load_dwordx4 %0, %1, off sc0 sc1"
               : "=v"(f.u) : "v"(p16));
  return f.v;
}

// Coherent-point 8B store (write-through past non-coherent L2).
static __device__ __forceinline__ void st_sys64(u16* p, unsigned long long v) {
  asm volatile("global_store_dwordx2 %0, %1, off sc0 sc1"
               :: "v"(p), "v"(v) : "memory");
}

static __device__ __forceinline__ float sigmoid_fast(float x) {
  return 1.0f / (1.0f + __expf(-x));
}
static __device__ __forceinline__ float tanh_fast(float x) {
  return 1.0f - 2.0f / (__expf(2.0f * x) + 1.0f);
}

// single-lane poll with backoff
static __device__ __forceinline__ void wait_ge(unsigned* p, unsigned tgt) {
  while (__hip_atomic_load(p, __ATOMIC_RELAXED, __HIP_MEMORY_SCOPE_AGENT) < tgt)
    __builtin_amdgcn_s_sleep(1);
}

// ---------------------------------------------------------------------------
// K1
// ---------------------------------------------------------------------------
__global__ void build_inputs(const float* __restrict__ features,
                             const int*   __restrict__ captions,
                             const float* __restrict__ embed_w,
                             u16* __restrict__ dst) {
  int idx = blockIdx.x * blockDim.x + threadIdx.x;
  const int n = NSTEP * BATCH * EMB;
  if (idx >= n) return;
  int e = idx & (EMB - 1);
  int rem = idx >> 9;
  int b = rem & (BATCH - 1);
  int t = rem >> 5;
  float v;
  if (t == 0) v = features[b * EMB + e];
  else        v = embed_w[(size_t)captions[b * SEQT + (t - 1)] * EMB + e];
  dst[idx] = f2bf(v);
}

// ---------------------------------------------------------------------------
// K2
// ---------------------------------------------------------------------------
__global__ void cast_bf16(const float* __restrict__ src, u16* __restrict__ dst, int n4) {
  int i = blockIdx.x * blockDim.x + threadIdx.x;
  if (i >= n4) return;
  float4 v = ((const float4*)src)[i];
  ushort4 o;
  o.x = f2bf(v.x); o.y = f2bf(v.y); o.z = f2bf(v.z); o.w = f2bf(v.w);
  ((ushort4*)dst)[i] = o;
}

__global__ void cast_pad_wout(const float* __restrict__ src, u16* __restrict__ dst) {
  int i = blockIdx.x * blockDim.x + threadIdx.x;
  const int n4 = VPAD * 512 / 4;
  const int nsrc4 = VOCAB * 512 / 4;
  if (i >= n4) return;
  ushort4 o;
  if (i < nsrc4) {
    float4 v = ((const float4*)src)[i];
    o.x = f2bf(v.x); o.y = f2bf(v.y); o.z = f2bf(v.z); o.w = f2bf(v.w);
  } else {
    o.x = 0; o.y = 0; o.z = 0; o.w = 0;
  }
  ((ushort4*)dst)[i] = o;
}

// ---------------------------------------------------------------------------
// K3: persistent pipelined 2-layer LSTM, per-layer counters, free-running L0.
// ---------------------------------------------------------------------------
__global__ __launch_bounds__(256)
__attribute__((amdgpu_waves_per_eu(1, 1)))
void lstm_pipeline(const u16* __restrict__ inputs_bf,   // [65][32][512]
                   const u16* __restrict__ wih0, const u16* __restrict__ whh0,
                   const float* __restrict__ b0,
                   const u16* __restrict__ wih1, const u16* __restrict__ whh1,
                   const float* __restrict__ b1,
                   u16* h0_all,                  // [65][32][512]
                   u16* h1_all,                  // [65][32][512]
                   u16* __restrict__ A_bf,       // [2048][512] rows (b*64+t)
                   unsigned* cnt) {              // cnt[0]=L0, cnt[32]=L1
  const int wg    = blockIdx.x;
  const int layer = wg >> 5;
  const int j0    = (wg & 31) * 16;
  const int tid   = threadIdx.x;
  const int lane  = tid & 63;
  const int wv    = tid >> 6;       // wave index == gate index
  const int l15   = lane & 15;
  const int lg    = lane >> 4;

  const u16*   wih  = layer ? wih1 : wih0;
  const u16*   whh  = layer ? whh1 : whh0;
  const float* bias = layer ? b1 : b0;
  unsigned* mycnt  = cnt + (layer ? 32 : 0);
  unsigned* cnt0   = cnt;
  const u16* xsrc  = layer ? h0_all : inputs_bf;   // same [t][b][512] layout
  const u16* hsrc  = layer ? h1_all : h0_all;
  u16*       hdst  = layer ? h1_all : h0_all;

  __shared__ float gates_lds[4][32][16];
  __shared__ float c_lds[32][16];
  __shared__ float bias_lds[4][16];

  for (int i = tid; i < BATCH * 16; i += 256) c_lds[i >> 4][i & 15] = 0.0f;
  if (tid < 64) bias_lds[tid >> 4][tid & 15] = bias[(tid >> 4) * HID + j0 + (tid & 15)];

  // Weight B-fragments in registers for all 65 steps.
  // B[k][n] = W[n][k]; lane l: n = wv*512 + j0 + l15, k = kk*32 + 8*lg + 0..7
  bf16x8 wif[16], whf[16];
  {
    const u16* wr = wih + (size_t)(wv * HID + j0 + l15) * 512;
    const u16* hr = whh + (size_t)(wv * HID + j0 + l15) * 512;
#pragma unroll
    for (int kk = 0; kk < 16; ++kk) {
      int k0 = kk * 32 + 8 * lg;
      wif[kk] = ld_frag(wr + k0);
      whf[kk] = ld_frag(hr + k0);
    }
  }
  __syncthreads();

  for (int t = 0; t < NSTEP; ++t) {
    // ---------------- X phase (before own-layer poll) ----------------
    if (layer == 1) {                 // need h0[t]; L0 runs ahead, usually no wait
      if (tid == 0) wait_ge(cnt0, 32u * (t + 1));
      __syncthreads();
    }
    f32x4 acc0 = {0.f, 0.f, 0.f, 0.f};
    f32x4 acc1 = {0.f, 0.f, 0.f, 0.f};
    {
      const u16* xr0 = xsrc + (size_t)t * (BATCH * HID) + (size_t)l15 * 512;
      const u16* xr1 = xr0 + 16 * 512;
      bf16x8 a0[16], a1[16];
      if (layer == 1) {
#pragma unroll
        for (int kk = 0; kk < 16; ++kk) {
          int k0 = kk * 32 + 8 * lg;
          a0[kk] = ld_frag_sys(xr0 + k0);
          a1[kk] = ld_frag_sys(xr1 + k0);
        }
      } else {
#pragma unroll
        for (int kk = 0; kk < 16; ++kk) {
          int k0 = kk * 32 + 8 * lg;
          a0[kk] = ld_frag(xr0 + k0);
          a1[kk] = ld_frag(xr1 + k0);
        }
      }
      asm volatile("s_waitcnt vmcnt(0)" ::: "memory");
      __builtin_amdgcn_sched_barrier(0);
#pragma unroll
      for (int kk = 0; kk < 16; ++kk) {
        acc0 = __builtin_amdgcn_mfma_f32_16x16x32_bf16(a0[kk], wif[kk], acc0, 0, 0, 0);
        acc1 = __builtin_amdgcn_mfma_f32_16x16x32_bf16(a1[kk], wif[kk], acc1, 0, 0, 0);
      }
    }
    // ---------------- H phase (after own-layer poll) ----------------
    if (t > 0) {
      if (tid == 0) wait_ge(mycnt, 32u * t);
      __syncthreads();
      const u16* hr0 = hsrc + (size_t)(t - 1) * (BATCH * HID) + (size_t)l15 * 512;
      const u16* hr1 = hr0 + 16 * 512;
      bf16x8 a0[16], a1[16];
#pragma unroll
      for (int kk = 0; kk < 16; ++kk) {
        int k0 = kk * 32 + 8 * lg;
        a0[kk] = ld_frag_sys(hr0 + k0);
        a1[kk] = ld_frag_sys(hr1 + k0);
      }
      asm volatile("s_waitcnt vmcnt(0)" ::: "memory");
      __builtin_amdgcn_sched_barrier(0);
#pragma unroll
      for (int kk = 0; kk < 16; ++kk) {
        acc0 = __builtin_amdgcn_mfma_f32_16x16x32_bf16(a0[kk], whf[kk], acc0, 0, 0, 0);
        acc1 = __builtin_amdgcn_mfma_f32_16x16x32_bf16(a1[kk], whf[kk], acc1, 0, 0, 0);
      }
    }
    // C layout: col = lane&15, row = 4*(lane>>4)+reg
#pragma unroll
    for (int rr = 0; rr < 4; ++rr) {
      gates_lds[wv][4 * lg + rr][l15]      = acc0[rr];
      gates_lds[wv][16 + 4 * lg + rr][l15] = acc1[rr];
    }
    __syncthreads();

    if (tid < 128) {
      const int b = tid >> 2;
      const int q = (tid & 3) * 4;
      float hv[4];
#pragma unroll
      for (int u = 0; u < 4; ++u) {
        const int jj = q + u;
        float gi = gates_lds[0][b][jj] + bias_lds[0][jj];
        float gf = gates_lds[1][b][jj] + bias_lds[1][jj];
        float gg = gates_lds[2][b][jj] + bias_lds[2][jj];
        float go = gates_lds[3][b][jj] + bias_lds[3][jj];
        float cp = c_lds[b][jj];
        float cn = sigmoid_fast(gf) * cp + sigmoid_fast(gi) * tanh_fast(gg);
        c_lds[b][jj] = cn;
        hv[u] = sigmoid_fast(go) * tanh_fast(cn);
      }
      union { ushort4 s; unsigned long long v; } pk;
      pk.s.x = f2bf(hv[0]); pk.s.y = f2bf(hv[1]);
      pk.s.z = f2bf(hv[2]); pk.s.w = f2bf(hv[3]);
      st_sys64(hdst + (size_t)t * (BATCH * HID) + b * HID + j0 + q, pk.v);
      if (layer == 1 && t >= 1)
        *(unsigned long long*)(A_bf + (size_t)(b * SEQT + (t - 1)) * HID + j0 + q) = pk.v;
    }
    // each wave drains its own stores to the coherent point, then signal
    asm volatile("s_waitcnt vmcnt(0)" ::: "memory");
    __syncthreads();
    if (tid == 0)
      __hip_atomic_fetch_add(mycnt, 1u, __ATOMIC_RELAXED, __HIP_MEMORY_SCOPE_AGENT);
  }
}

// ---------------------------------------------------------------------------
// K4: logits GEMM (unchanged this round).
// ---------------------------------------------------------------------------
__global__ __launch_bounds__(256)
void logits_gemm(const u16* __restrict__ Ag,
                 const u16* __restrict__ Bg,
                 const float* __restrict__ b_out,
                 float* __restrict__ out) {
  const int mt = blockIdx.x;
  const int nt = blockIdx.y;
  const int m0 = mt * 128, v0 = nt * 128;
  const int tid  = threadIdx.x;
  const int lane = tid & 63;
  const int wv   = tid >> 6;
  const int l15  = lane & 15;
  const int lg   = lane >> 4;
  const int wm = (wv & 1) * 64;
  const int wn = (wv >> 1) * 64;

  __shared__ u16 As[128 * 32];
  __shared__ u16 Bs[128 * 32];

  f32x4 acc[4][4];
#pragma unroll
  for (int mi = 0; mi < 4; ++mi)
#pragma unroll
    for (int ni = 0; ni < 4; ++ni)
      acc[mi][ni] = (f32x4){0.f, 0.f, 0.f, 0.f};

  for (int kt = 0; kt < 16; ++kt) {
#pragma unroll
    for (int c = 0; c < 2; ++c) {
      int f16 = wv * 128 + c * 64 + lane;
      int row = f16 >> 2;
      int kc  = (f16 & 3) << 3;
      const u16* ga = Ag + (size_t)(m0 + row) * 512 + kt * 32 + kc;
      const u16* gb = Bg + (size_t)(v0 + row) * 512 + kt * 32 + kc;
      u16* la = &As[(wv * 128 + c * 64) * 8];
      u16* lb = &Bs[(wv * 128 + c * 64) * 8];
      __builtin_amdgcn_global_load_lds(
          (const __attribute__((address_space(1))) void*)ga,
          (__attribute__((address_space(3))) void*)la, 16, 0, 0);
      __builtin_amdgcn_global_load_lds(
          (const __attribute__((address_space(1))) void*)gb,
          (__attribute__((address_space(3))) void*)lb, 16, 0, 0);
    }
    asm volatile("s_waitcnt vmcnt(0)" ::: "memory");
    __syncthreads();

    bf16x8 af[4], bfr[4];
#pragma unroll
    for (int i = 0; i < 4; ++i) {
      af[i]  = ld_frag(&As[(wm + i * 16 + l15) * 32 + 8 * lg]);
      bfr[i] = ld_frag(&Bs[(wn + i * 16 + l15) * 32 + 8 * lg]);
    }
#pragma unroll
    for (int mi = 0; mi < 4; ++mi)
#pragma unroll
      for (int ni = 0; ni < 4; ++ni)
        acc[mi][ni] = __builtin_amdgcn_mfma_f32_16x16x32_bf16(af[mi], bfr[ni], acc[mi][ni], 0, 0, 0);
    __syncthreads();
  }

#pragma unroll
  for (int ni = 0; ni < 4; ++ni) {
    int v = v0 + wn + ni * 16 + l15;
    bool vok = (v < VOCAB);
    float bo = vok ? b_out[v] : 0.0f;
#pragma unroll
    for (int mi = 0; mi < 4; ++mi) {
      int mbase = m0 + wm + mi * 16 + 4 * lg;
#pragma unroll
      for (int rr = 0; rr < 4; ++rr) {
        if (vok) out[(size_t)(mbase + rr) * VOCAB + v] = acc[mi][ni][rr] + bo;
      }
    }
  }
}

// ---------------------------------------------------------------------------
// host
// ---------------------------------------------------------------------------
extern "C" void kernel_launch(void* const* d_in, const int* in_sizes, int n_in,
                              void* d_out, int out_size, void* d_ws, size_t ws_size,
                              hipStream_t stream) {
  const float* features = (const float*)d_in[0];
  const int*   captions = (const int*)d_in[1];
  const float* embed_w  = (const float*)d_in[2];
  const float* w_ih0    = (const float*)d_in[3];
  const float* w_hh0    = (const float*)d_in[4];
  const float* b0       = (const float*)d_in[5];
  const float* w_ih1    = (const float*)d_in[6];
  const float* w_hh1    = (const float*)d_in[7];
  const float* b1       = (const float*)d_in[8];
  const float* w_out    = (const float*)d_in[9];
  const float* b_out    = (const float*)d_in[10];
  float* out = (float*)d_out;

  char* ws = (char*)d_ws;
  size_t off = 0;
  auto alloc = [&](size_t bytes) -> void* {
    void* p = ws + off;
    off = (off + bytes + 255) & ~(size_t)255;
    return p;
  };
  unsigned* cnt  = (unsigned*)alloc(256);
  u16* inputs_bf = (u16*)alloc((size_t)NSTEP * BATCH * EMB * 2);
  u16* wih0_bf   = (u16*)alloc((size_t)4 * HID * EMB * 2);
  u16* whh0_bf   = (u16*)alloc((size_t)4 * HID * HID * 2);
  u16* wih1_bf   = (u16*)alloc((size_t)4 * HID * HID * 2);
  u16* whh1_bf   = (u16*)alloc((size_t)4 * HID * HID * 2);
  u16* wout_bf   = (u16*)alloc((size_t)VPAD * HID * 2);
  u16* h0_all    = (u16*)alloc((size_t)NSTEP * BATCH * HID * 2);
  u16* h1_all    = (u16*)alloc((size_t)NSTEP * BATCH * HID * 2);
  u16* A_bf      = (u16*)alloc((size_t)BATCH * SEQT * HID * 2);
  (void)ws_size; (void)in_sizes; (void)n_in; (void)out_size;

  hipMemsetAsync(cnt, 0, 256, stream);

  {
    int n = NSTEP * BATCH * EMB;
    build_inputs<<<(n + 255) / 256, 256, 0, stream>>>(features, captions, embed_w, inputs_bf);
  }
  {
    int n4 = 4 * HID * EMB / 4;
    cast_bf16<<<(n4 + 255) / 256, 256, 0, stream>>>(w_ih0, wih0_bf, n4);
    cast_bf16<<<(n4 + 255) / 256, 256, 0, stream>>>(w_hh0, whh0_bf, n4);
    cast_bf16<<<(n4 + 255) / 256, 256, 0, stream>>>(w_ih1, wih1_bf, n4);
    cast_bf16<<<(n4 + 255) / 256, 256, 0, stream>>>(w_hh1, whh1_bf, n4);
  }
  {
    int n4 = VPAD * 512 / 4;
    cast_pad_wout<<<(n4 + 255) / 256, 256, 0, stream>>>(w_out, wout_bf);
  }
  lstm_pipeline<<<NWG_LSTM, 256, 0, stream>>>(
      inputs_bf, wih0_bf, whh0_bf, b0, wih1_bf, whh1_bf, b1,
      h0_all, h1_all, A_bf, cnt);
  {
    dim3 grid(16, 393, 1);
    logits_gemm<<<grid, 256, 0, stream>>>(A_bf, wout_bf, b_out, out);
  }
}